// Round 5
// baseline (364.779 us; speedup 1.0000x reference)
//
#include <hip/hip_runtime.h>

// NGH=7, SUBQ=8, SUBD=1, POS_D=3, NEG_D=5, BORDER=16, SUBD_NEG=8. B=4,C=128,H=W=256.
#define CCH   128
#define HH    256
#define WW    256
#define BB    4
#define H1    28
#define W1    28
#define QTOT  3136
#define NPOS  29
#define NNEG  80
#define NDIS  3136
#define DT64  (NDIS / 64)   // 49 distractor tiles
#define QT64  (QTOT / 64)   // 49 query tiles
#define SCOLS 3217          // 1 + NNEG + NDIS

typedef short s8v __attribute__((ext_vector_type(8)));   // 8 bf16 (4 VGPRs)
typedef float f4v __attribute__((ext_vector_type(4)));   // MFMA accumulator
typedef float f4raw __attribute__((ext_vector_type(4))); // nontemporal-load-safe f32x4
typedef float f4u __attribute__((ext_vector_type(4), aligned(4)));  // 4B-aligned f32x4
typedef unsigned int u2v __attribute__((ext_vector_type(2)));

__device__ __forceinline__ unsigned short f2bf(float f) {  // RNE fp32->bf16
  unsigned int u = __float_as_uint(f);
  u += 0x7fffu + ((u >> 16) & 1u);
  return (unsigned short)(u >> 16);
}
__device__ __forceinline__ float bflo(unsigned int v) { return __uint_as_float(v << 16); }
__device__ __forceinline__ float bfhi(unsigned int v) { return __uint_as_float(v & 0xffff0000u); }

// Offsets in exact reference enumeration order (j outer asc, i inner asc).
__constant__ int POS_I[NPOS] = {
  0, -2,-1,0,1,2, -2,-1,0,1,2, -3,-2,-1,0,1,2,3, -2,-1,0,1,2, -2,-1,0,1,2, 0};
__constant__ int POS_J[NPOS] = {
  -3, -2,-2,-2,-2,-2, -1,-1,-1,-1,-1, 0,0,0,0,0,0,0, 1,1,1,1,1, 2,2,2,2,2, 3};
__constant__ int NEG_I[NNEG] = {
  0, -3,-2,-1,0,1,2,3, -4,-3,-2,-1,0,1,2,3,4, -5,-4,-3,3,4,5, -6,-5,-4,4,5,6,
  -6,-5,5,6, -6,-5,5,6, -7,-6,-5,5,6,7, -6,-5,5,6, -6,-5,5,6, -6,-5,-4,4,5,6,
  -5,-4,-3,3,4,5, -4,-3,-2,-1,0,1,2,3,4, -3,-2,-1,0,1,2,3, 0};
__constant__ int NEG_J[NNEG] = {
  -7, -6,-6,-6,-6,-6,-6,-6, -5,-5,-5,-5,-5,-5,-5,-5,-5, -4,-4,-4,-4,-4,-4,
  -3,-3,-3,-3,-3,-3, -2,-2,-2,-2, -1,-1,-1,-1, 0,0,0,0,0,0, 1,1,1,1, 2,2,2,2,
  3,3,3,3,3,3, 4,4,4,4,4,4, 5,5,5,5,5,5,5,5,5, 6,6,6,6,6,6,6, 7};

// ---- Kernel S: coalesced F1bf / X2 / Y2 / mask staging ----
// One block per (grid-y row, batch). Replaces the 128KB-strided scalar scatter
// that previously ran inside qualifying transpose blocks (straggler tail).
__global__ __launch_bounds__(256)
void stage_kernel(const float* __restrict__ feat1,
                  const float* __restrict__ aflow,
                  unsigned short* __restrict__ F1bf,
                  int* __restrict__ X2, int* __restrict__ Y2,
                  float* __restrict__ mask_out) {
  __shared__ float sf1[28][130];   // stride 130: phase-B b64 aligned, banks vary
  __shared__ float sxy[2][28];

  int ygrid = blockIdx.x, b = blockIdx.y;
  int y = 16 + 8 * ygrid;
  int w = threadIdx.x >> 6, l = threadIdx.x & 63;

  // Phase A: wave w loads channels 32w..32w+31, x-coalesced 64-wide chunks.
  const float* f1r = feat1 + ((size_t)(b * CCH + 32 * w) * HH + y) * WW;
  for (int i = 0; i < 32; ++i) {
    float v[4];
    #pragma unroll
    for (int ch = 0; ch < 4; ++ch)       // 4 independent loads in flight
      v[ch] = f1r[(size_t)i * HH * WW + 16 + 64 * ch + l];
    if ((l & 7) == 0) {                  // lanes on the 8-stride grid points
      #pragma unroll
      for (int ch = 0; ch < 4; ++ch) {
        int xsi = 8 * ch + (l >> 3);
        if (xsi < 28) sf1[xsi][32 * w + i] = v[ch];
      }
    }
  }
  if (w < 2) {                            // aflow component w, same extraction
    const float* ar = aflow + ((size_t)(b * 2 + w) * HH + y) * WW;
    #pragma unroll
    for (int ch = 0; ch < 4; ++ch) {
      float v = ar[16 + 64 * ch + l];
      int xsi = 8 * ch + (l >> 3);
      if ((l & 7) == 0 && xsi < 28) sxy[w][xsi] = v;
    }
  }
  __syncthreads();

  // Phase B: pack bf16 pairs, coalesced 256 B per query.
  int qbase = b * H1 * W1 + ygrid * W1;
  #pragma unroll
  for (int k = 0; k < 7; ++k) {          // 28 queries x 64 dwords = 1792
    int idx = k * 256 + threadIdx.x;
    int q28 = idx >> 6, cp = idx & 63;
    unsigned lo = f2bf(sf1[q28][2 * cp]);
    unsigned hi = f2bf(sf1[q28][2 * cp + 1]);
    ((unsigned int*)(F1bf + (size_t)(qbase + q28) * CCH))[cp] = lo | (hi << 16);
  }
  if (threadIdx.x < 28) {
    int q = qbase + threadIdx.x;
    int px = (int)(sxy[0][threadIdx.x] + 0.5f);
    int py = (int)(sxy[1][threadIdx.x] + 0.5f);
    X2[q] = px; Y2[q] = py;
    mask_out[q] = (px >= 0 && py >= 0 && px < WW && py < HH) ? 1.0f : 0.0f;
  }
}

// ---- Kernel T: feat2 NCHW fp32 -> NHWC bf16, fused F2bf staging ----
// v3: f1/aflow staging removed (now kernel S) -> no straggler blocks.
__global__ __launch_bounds__(256, 6)
void transpose_kernel(const float* __restrict__ feat2,
                      unsigned short* __restrict__ feat2T,
                      unsigned short* __restrict__ F2bf) {
  // stride 66 dwords: store banks = (8*xq + cp) % 32 -> 2 lanes/bank (free);
  // read b64 banks: exactly 4 dwords/bank/instr = LDS throughput minimum.
  __shared__ __align__(16) unsigned int tile[2][32][66];

  int x0 = blockIdx.x * 32;
  int y0 = blockIdx.y * 2;
  int b  = blockIdx.z;
  int tid = threadIdx.x;
  int cp = tid >> 3;        // channel-pair index within half (0..31)
  int xq = tid & 7;         // float4 quad within 32-wide x tile

  // Phase 1: issue all 8 float4 loads before any use (8 VMEM in flight/thread).
  const float* fbase = feat2 + (size_t)b * CCH * HH * WW;
  f4raw v[2][2][2];         // [row][half][c parity]
  #pragma unroll
  for (int r = 0; r < 2; ++r)
    #pragma unroll
    for (int h = 0; h < 2; ++h) {
      int c0 = 2 * (h * 32 + cp);
      const float* p = fbase + ((size_t)c0 * HH + (y0 + r)) * WW + x0 + 4 * xq;
      v[r][h][0] = __builtin_nontemporal_load((const f4raw*)p);
      v[r][h][1] = __builtin_nontemporal_load((const f4raw*)(p + (size_t)HH * WW));
    }

  // Convert + packed dword stores (channel pair -> one LDS dword).
  #pragma unroll
  for (int r = 0; r < 2; ++r)
    #pragma unroll
    for (int h = 0; h < 2; ++h) {
      int cpf = h * 32 + cp;
      f4raw a = v[r][h][0], c = v[r][h][1];
      tile[r][4 * xq + 0][cpf] = (unsigned)f2bf(a.x) | ((unsigned)f2bf(c.x) << 16);
      tile[r][4 * xq + 1][cpf] = (unsigned)f2bf(a.y) | ((unsigned)f2bf(c.y) << 16);
      tile[r][4 * xq + 2][cpf] = (unsigned)f2bf(a.z) | ((unsigned)f2bf(c.z) << 16);
      tile[r][4 * xq + 3][cpf] = (unsigned)f2bf(a.w) | ((unsigned)f2bf(c.w) << 16);
    }
  __syncthreads();

  // Phase 2: each thread emits 32 B (16 channels) of one pixel, b64 LDS reads.
  int xi = tid >> 3;        // 0..31
  int cg = (tid & 7) * 8;   // dword index within the 64-dword channel row
  #pragma unroll
  for (int r = 0; r < 2; ++r) {
    u2v t0 = *(const u2v*)&tile[r][xi][cg + 0];
    u2v t1 = *(const u2v*)&tile[r][xi][cg + 2];
    u2v t2 = *(const u2v*)&tile[r][xi][cg + 4];
    u2v t3 = *(const u2v*)&tile[r][xi][cg + 6];
    unsigned int* dst = (unsigned int*)(feat2T +
        ((size_t)((b * HH + y0 + r) * WW) + x0 + xi) * CCH) + cg;
    ((uint4*)dst)[0] = make_uint4(t0.x, t0.y, t1.x, t1.y);
    ((uint4*)dst)[1] = make_uint4(t2.x, t2.y, t3.x, t3.y);
  }

  // F2bf staging straight from packed tile (cheap: LDS read + coalesced store).
  #pragma unroll
  for (int r = 0; r < 2; ++r) {
    int y = y0 + r;
    if ((y & 7) == 0 && y >= 16 && y <= 232) {
      int xs = x0 + (tid >> 6) * 8;         // 4 grid-x candidates per block
      if (xs >= 16 && xs <= 232) {
        int cpq = tid & 63;                 // channel pair 0..63
        int q = b * H1 * W1 + ((y - 16) >> 3) * W1 + ((xs - 16) >> 3);
        ((unsigned int*)(F2bf + (size_t)q * CCH))[cpq] = tile[r][xs - x0][cpq];
      }
    }
  }
}

// ---- Kernel M: fused posneg (blocks 0..QTOT-1) + dscore (blocks QTOT..) ----
__global__ void main_kernel(const unsigned short* __restrict__ feat2T,
                            const float* __restrict__ conf1,
                            const float* __restrict__ conf2,
                            const unsigned short* __restrict__ F1bf,
                            const unsigned short* __restrict__ F2bf,
                            const int* __restrict__ X2, const int* __restrict__ Y2,
                            float* __restrict__ scores, float* __restrict__ gt,
                            float* __restrict__ qconf_out) {
  __shared__ union {
    // tile stride 68: 16B-aligned rows for b128 readout (row*68+col4 ≡ 0 mod 4),
    // MFMA-stage banks: +4 rows = 272 dw ≡ 16 mod 32 -> 2 lanes/bank (free).
    struct { __align__(16) float tile[64][68]; int sx2[64]; int sy2[64]; } ds;
    struct { __align__(16) float f1s[CCH]; float posv[NPOS]; float negv[NNEG];
             float bestv; } pn;
  } sm;

  if (blockIdx.x < QTOT) {
    // ---------------- posneg branch ----------------
    int q = blockIdx.x, t = threadIdx.x;
    int b = q / (H1 * W1), r = q % (H1 * W1);
    int y = 16 + 8 * (r / W1);
    int x = 16 + 8 * (r % W1);

    if (t < 64) {                          // coalesced 256 B f1 row -> LDS fp32
      unsigned int u = ((const unsigned int*)(F1bf + (size_t)q * CCH))[t];
      sm.pn.f1s[2 * t]     = bflo(u);
      sm.pn.f1s[2 * t + 1] = bfhi(u);
    }
    int x2 = X2[q], y2 = Y2[q];            // L2-broadcast
    __syncthreads();

    if (t < 2 * (NPOS + NNEG)) {           // 218 threads: 2 per offset, 64 ch each
      int off = t >> 1, half = t & 1;
      int di = (off < NPOS) ? POS_I[off] : NEG_I[off - NPOS];
      int dj = (off < NPOS) ? POS_J[off] : NEG_J[off - NPOS];
      int xk = min(max(x2 + di, 0), WW - 1);
      int yk = min(max(y2 + dj, 0), HH - 1);
      const uint4* p4 = (const uint4*)(feat2T +
          ((size_t)((b * HH + yk) * WW) + xk) * CCH + half * 64);
      float acc = 0.f;
      #pragma unroll
      for (int i = 0; i < 8; ++i) {        // 8 x 16 B contiguous bf16
        uint4 v = p4[i];
        float4 fa = *(const float4*)&sm.pn.f1s[half * 64 + i * 8];
        float4 fb = *(const float4*)&sm.pn.f1s[half * 64 + i * 8 + 4];
        acc += fa.x * bflo(v.x) + fa.y * bfhi(v.x)
             + fa.z * bflo(v.y) + fa.w * bfhi(v.y)
             + fb.x * bflo(v.z) + fb.y * bfhi(v.z)
             + fb.z * bflo(v.w) + fb.w * bfhi(v.w);
      }
      acc += __shfl_xor(acc, 1);           // combine halves (adjacent lanes)
      if (half == 0) {
        if (off < NPOS) sm.pn.posv[off] = acc;
        else            sm.pn.negv[off - NPOS] = acc;
      }
    }
    if (t < 1 + NNEG)
      gt[(size_t)q * SCOLS + t] = (t == 0) ? 1.0f : 0.0f;
    __syncthreads();

    if (t < 32) {                          // wave-parallel argmax (first occurrence)
      float bv = (t < NPOS) ? sm.pn.posv[t] : -3.4e38f;
      int bi = t;
      #pragma unroll
      for (int s = 16; s; s >>= 1) {       // butterfly: all 32 lanes converge
        float ov = __shfl_xor(bv, s);
        int oi = __shfl_xor(bi, s);
        if (ov > bv || (ov == bv && oi < bi)) { bv = ov; bi = oi; }
      }
      if (t == 0) {
        sm.pn.bestv = bv;
        int sx = min(max(x2 + POS_I[bi], 0), WW - 1);
        int sy = min(max(y2 + POS_J[bi], 0), HH - 1);
        float c1 = conf1[((size_t)b * HH + y) * WW + x];
        float c2 = conf2[((size_t)b * HH + sy) * WW + sx];
        qconf_out[q] = 0.5f * (c1 + c2);
      }
    }
    __syncthreads();

    if (t < 1 + NNEG)                      // coalesced 324 B head write
      scores[(size_t)q * SCOLS + t] = (t == 0) ? sm.pn.bestv : sm.pn.negv[t - 1];

  } else {
    // ---------------- dscore branch (bf16 MFMA 64q x 64d) ----------------
    int bid = blockIdx.x - QTOT;
    int qb = (bid / DT64) * 64;
    int db = (bid % DT64) * 64;
    int w = threadIdx.x >> 6, lane = threadIdx.x & 63;
    int m  = lane & 15;
    int ko = (lane >> 4) * 8;

    if (threadIdx.x < 64) {
      sm.ds.sx2[threadIdx.x] = X2[qb + threadIdx.x];
      sm.ds.sy2[threadIdx.x] = Y2[qb + threadIdx.x];
    }

    f4v acc[4];
    #pragma unroll
    for (int dt = 0; dt < 4; ++dt) acc[dt] = (f4v){0.f, 0.f, 0.f, 0.f};

    #pragma unroll
    for (int kk = 0; kk < 4; ++kk) {
      s8v a = *(const s8v*)(F1bf + (size_t)(qb + w * 16 + m) * CCH + kk * 32 + ko);
      #pragma unroll
      for (int dt = 0; dt < 4; ++dt) {
        s8v bfr = *(const s8v*)(F2bf + (size_t)(db + dt * 16 + m) * CCH + kk * 32 + ko);
        acc[dt] = __builtin_amdgcn_mfma_f32_16x16x32_bf16(a, bfr, acc[dt], 0, 0, 0);
      }
    }

    // Stage to LDS (C/D layout: col = lane&15, row = (lane>>4)*4 + reg).
    int rbase = (lane >> 4) * 4, col = lane & 15;
    #pragma unroll
    for (int dt = 0; dt < 4; ++dt)
      #pragma unroll
      for (int r = 0; r < 4; ++r)
        sm.ds.tile[w * 16 + rbase + r][dt * 16 + col] = acc[dt][r];
    __syncthreads();

    // Vectorized epilogue: thread owns 4 cols x 4 row-passes -> dwordx4 stores.
    int col4  = (threadIdx.x & 15) * 4;
    int rslot = threadIdx.x >> 4;          // 0..15
    int dxs[4], dys[4], dbats[4];
    #pragma unroll
    for (int k = 0; k < 4; ++k) {
      int d = db + col4 + k;
      int dbat = d / (H1 * W1), dr = d % (H1 * W1);
      dys[k] = 16 + 8 * (dr / W1);
      dxs[k] = 16 + 8 * (dr % W1);
      dbats[k] = dbat;
    }
    #pragma unroll
    for (int p = 0; p < 4; ++p) {
      int row = p * 16 + rslot;
      int q = qb + row;
      int qbat = q / (H1 * W1);
      int sx = sm.ds.sx2[row], sy = sm.ds.sy2[row];
      f4raw vv = *(const f4raw*)&sm.ds.tile[row][col4];   // 16B-aligned b128
      #pragma unroll
      for (int k = 0; k < 4; ++k) {
        int ddx = dxs[k] - sx, ddy = dys[k] - sy;
        int dis2 = ddx * ddx + ddy * ddy + (dbats[k] != qbat ? 25 : 0);  // NEG_D^2
        if (dis2 < 25) vv[k] = 0.f;
      }
      size_t o = (size_t)q * SCOLS + 1 + NNEG + db + col4;  // 4B-aligned (SCOLS odd)
      __builtin_nontemporal_store(vv, (f4u*)&scores[o]);
      __builtin_nontemporal_store((f4u){0.f, 0.f, 0.f, 0.f}, (f4u*)&gt[o]);
    }
  }
}

extern "C" void kernel_launch(void* const* d_in, const int* in_sizes, int n_in,
                              void* d_out, int out_size, void* d_ws, size_t ws_size,
                              hipStream_t stream) {
  const float* feat1 = (const float*)d_in[0];
  const float* feat2 = (const float*)d_in[1];
  const float* conf1 = (const float*)d_in[2];
  const float* conf2 = (const float*)d_in[3];
  const float* aflow = (const float*)d_in[4];

  float* out       = (float*)d_out;
  float* scores    = out;
  float* gt        = out + (size_t)QTOT * SCOLS;
  float* mask_out  = out + 2 * (size_t)QTOT * SCOLS;
  float* qconf_out = mask_out + QTOT;

  unsigned short* feat2T = (unsigned short*)d_ws;                 // B*H*W*C bf16
  unsigned short* F1bf   = feat2T + (size_t)BB * HH * WW * CCH;
  unsigned short* F2bf   = F1bf + (size_t)QTOT * CCH;
  int* X2 = (int*)(F2bf + (size_t)QTOT * CCH);
  int* Y2 = X2 + QTOT;

  dim3 gS(H1, BB);
  stage_kernel<<<gS, 256, 0, stream>>>(feat1, aflow, F1bf, X2, Y2, mask_out);
  dim3 gT(WW / 32, HH / 2, BB);
  transpose_kernel<<<gT, 256, 0, stream>>>(feat2, feat2T, F2bf);
  main_kernel<<<QTOT + DT64 * QT64, 256, 0, stream>>>(feat2T, conf1, conf2,
                                                      F1bf, F2bf, X2, Y2,
                                                      scores, gt, qconf_out);
}

// Round 6
// 333.367 us; speedup vs baseline: 1.0942x; 1.0942x over previous
//
#include <hip/hip_runtime.h>

// NGH=7, SUBQ=8, SUBD=1, POS_D=3, NEG_D=5, BORDER=16, SUBD_NEG=8. B=4,C=128,H=W=256.
#define CCH   128
#define HH    256
#define WW    256
#define BB    4
#define H1    28
#define W1    28
#define QTOT  3136
#define NPOS  29
#define NNEG  80
#define NDIS  3136
#define DT64  (NDIS / 64)   // 49 distractor tiles
#define QT64  (QTOT / 64)   // 49 query tiles
#define SCOLS 3217          // 1 + NNEG + NDIS

typedef short s8v __attribute__((ext_vector_type(8)));   // 8 bf16 (4 VGPRs)
typedef float f4v __attribute__((ext_vector_type(4)));   // MFMA accumulator
typedef float f4raw __attribute__((ext_vector_type(4))); // nontemporal-load-safe f32x4
typedef float f4u __attribute__((ext_vector_type(4), aligned(4)));  // 4B-aligned f32x4
typedef unsigned int u2v __attribute__((ext_vector_type(2)));

__device__ __forceinline__ unsigned short f2bf(float f) {  // RNE fp32->bf16
  unsigned int u = __float_as_uint(f);
  u += 0x7fffu + ((u >> 16) & 1u);
  return (unsigned short)(u >> 16);
}
__device__ __forceinline__ float bflo(unsigned int v) { return __uint_as_float(v << 16); }
__device__ __forceinline__ float bfhi(unsigned int v) { return __uint_as_float(v & 0xffff0000u); }

// Offsets in exact reference enumeration order (j outer asc, i inner asc).
__constant__ int POS_I[NPOS] = {
  0, -2,-1,0,1,2, -2,-1,0,1,2, -3,-2,-1,0,1,2,3, -2,-1,0,1,2, -2,-1,0,1,2, 0};
__constant__ int POS_J[NPOS] = {
  -3, -2,-2,-2,-2,-2, -1,-1,-1,-1,-1, 0,0,0,0,0,0,0, 1,1,1,1,1, 2,2,2,2,2, 3};
__constant__ int NEG_I[NNEG] = {
  0, -3,-2,-1,0,1,2,3, -4,-3,-2,-1,0,1,2,3,4, -5,-4,-3,3,4,5, -6,-5,-4,4,5,6,
  -6,-5,5,6, -6,-5,5,6, -7,-6,-5,5,6,7, -6,-5,5,6, -6,-5,5,6, -6,-5,-4,4,5,6,
  -5,-4,-3,3,4,5, -4,-3,-2,-1,0,1,2,3,4, -3,-2,-1,0,1,2,3, 0};
__constant__ int NEG_J[NNEG] = {
  -7, -6,-6,-6,-6,-6,-6,-6, -5,-5,-5,-5,-5,-5,-5,-5,-5, -4,-4,-4,-4,-4,-4,
  -3,-3,-3,-3,-3,-3, -2,-2,-2,-2, -1,-1,-1,-1, 0,0,0,0,0,0, 1,1,1,1, 2,2,2,2,
  3,3,3,3,3,3, 4,4,4,4,4,4, 5,5,5,5,5,5,5,5,5, 6,6,6,6,6,6,6, 7};

// ---- Kernel T: feat2 NCHW fp32 -> NHWC bf16, fused F1bf/F2bf/xy2/mask staging ----
// v2 (R3 best-measured): 2 y-rows/block, 8 buffered float4 loads/thread,
//     LDS layout [row][x][c-pair] (dword-packed) -> conflict-free b32 stores,
//     read-out via 4x ds_read_b64. Fused staging kept in-kernel (R5 split hurt).
__global__ __launch_bounds__(256, 6)
void transpose_kernel(const float* __restrict__ feat2,
                      const float* __restrict__ feat1,
                      const float* __restrict__ aflow,
                      unsigned short* __restrict__ feat2T,
                      unsigned short* __restrict__ F1bf,
                      unsigned short* __restrict__ F2bf,
                      int* __restrict__ X2, int* __restrict__ Y2,
                      float* __restrict__ mask_out) {
  // stride 66 dwords: store banks = (8*xq + cp) % 32 -> 2 lanes/bank (free);
  // read b64 banks: exactly 4 dwords/bank/instr = LDS throughput minimum.
  __shared__ __align__(16) unsigned int tile[2][32][66];

  int x0 = blockIdx.x * 32;
  int y0 = blockIdx.y * 2;
  int b  = blockIdx.z;
  int tid = threadIdx.x;
  int cp = tid >> 3;        // channel-pair index within half (0..31)
  int xq = tid & 7;         // float4 quad within 32-wide x tile

  // Phase 1: issue all 8 float4 loads before any use (8 VMEM in flight/thread).
  const float* fbase = feat2 + (size_t)b * CCH * HH * WW;
  f4raw v[2][2][2];         // [row][half][c parity]
  #pragma unroll
  for (int r = 0; r < 2; ++r)
    #pragma unroll
    for (int h = 0; h < 2; ++h) {
      int c0 = 2 * (h * 32 + cp);
      const float* p = fbase + ((size_t)c0 * HH + (y0 + r)) * WW + x0 + 4 * xq;
      v[r][h][0] = __builtin_nontemporal_load((const f4raw*)p);
      v[r][h][1] = __builtin_nontemporal_load((const f4raw*)(p + (size_t)HH * WW));
    }

  // Convert + packed dword stores (channel pair -> one LDS dword).
  #pragma unroll
  for (int r = 0; r < 2; ++r)
    #pragma unroll
    for (int h = 0; h < 2; ++h) {
      int cpf = h * 32 + cp;
      f4raw a = v[r][h][0], c = v[r][h][1];
      tile[r][4 * xq + 0][cpf] = (unsigned)f2bf(a.x) | ((unsigned)f2bf(c.x) << 16);
      tile[r][4 * xq + 1][cpf] = (unsigned)f2bf(a.y) | ((unsigned)f2bf(c.y) << 16);
      tile[r][4 * xq + 2][cpf] = (unsigned)f2bf(a.z) | ((unsigned)f2bf(c.z) << 16);
      tile[r][4 * xq + 3][cpf] = (unsigned)f2bf(a.w) | ((unsigned)f2bf(c.w) << 16);
    }
  __syncthreads();

  // Phase 2: each thread emits 32 B (16 channels) of one pixel, b64 LDS reads.
  int xi = tid >> 3;        // 0..31
  int cg = (tid & 7) * 8;   // dword index within the 64-dword channel row
  #pragma unroll
  for (int r = 0; r < 2; ++r) {
    u2v t0 = *(const u2v*)&tile[r][xi][cg + 0];
    u2v t1 = *(const u2v*)&tile[r][xi][cg + 2];
    u2v t2 = *(const u2v*)&tile[r][xi][cg + 4];
    u2v t3 = *(const u2v*)&tile[r][xi][cg + 6];
    unsigned int* dst = (unsigned int*)(feat2T +
        ((size_t)((b * HH + y0 + r) * WW) + x0 + xi) * CCH) + cg;
    ((uint4*)dst)[0] = make_uint4(t0.x, t0.y, t1.x, t1.y);
    ((uint4*)dst)[1] = make_uint4(t2.x, t2.y, t3.x, t3.y);
  }

  // Grid-point staging: F2bf straight from packed tile, F1bf from feat1,
  // xy2/mask from aflow. At most one qualifying row per block.
  #pragma unroll
  for (int r = 0; r < 2; ++r) {
    int y = y0 + r;
    if ((y & 7) == 0 && y >= 16 && y <= 232) {
      int xs = x0 + (tid >> 6) * 8;         // 4 grid-x candidates per block
      if (xs >= 16 && xs <= 232) {
        int cpq = tid & 63;                 // channel pair 0..63
        int q = b * H1 * W1 + ((y - 16) >> 3) * W1 + ((xs - 16) >> 3);
        ((unsigned int*)(F2bf + (size_t)q * CCH))[cpq] = tile[r][xs - x0][cpq];
        const float* f1p = feat1 + ((size_t)(b * CCH + 2 * cpq) * HH + y) * WW + xs;
        unsigned int l1 = f2bf(f1p[0]);
        unsigned int h1 = f2bf(f1p[(size_t)HH * WW]);
        ((unsigned int*)(F1bf + (size_t)q * CCH))[cpq] = l1 | (h1 << 16);
        if (cpq == 0) {
          float ax = aflow[((size_t)(b * 2 + 0) * HH + y) * WW + xs];
          float ay = aflow[((size_t)(b * 2 + 1) * HH + y) * WW + xs];
          int px = (int)(ax + 0.5f);
          int py = (int)(ay + 0.5f);
          X2[q] = px; Y2[q] = py;
          mask_out[q] = (px >= 0 && py >= 0 && px < WW && py < HH) ? 1.0f : 0.0f;
        }
      }
    }
  }
}

// ---- Kernel M: fused posneg (blocks 0..QTOT-1) + dscore (blocks QTOT..) ----
// gt is zeroed by hipMemsetAsync in kernel_launch; kernels write only gt[q][0]=1.
__global__ void main_kernel(const unsigned short* __restrict__ feat2T,
                            const float* __restrict__ conf1,
                            const float* __restrict__ conf2,
                            const unsigned short* __restrict__ F1bf,
                            const unsigned short* __restrict__ F2bf,
                            const int* __restrict__ X2, const int* __restrict__ Y2,
                            float* __restrict__ scores, float* __restrict__ gt,
                            float* __restrict__ qconf_out) {
  __shared__ union {
    // tile stride 68: rows 16B-aligned for b128 readout;
    // MFMA-stage banks: 68*4 dw = 272 ≡ 16 mod 32 -> 2 lanes/bank (free).
    struct { __align__(16) float tile[64][68]; int sx2[64]; int sy2[64]; } ds;
    struct { __align__(16) float f1s[CCH]; float posv[NPOS]; float negv[NNEG];
             float bestv; } pn;
  } sm;

  if (blockIdx.x < QTOT) {
    // ---------------- posneg branch ----------------
    int q = blockIdx.x, t = threadIdx.x;
    int b = q / (H1 * W1), r = q % (H1 * W1);
    int y = 16 + 8 * (r / W1);
    int x = 16 + 8 * (r % W1);

    if (t < 64) {                          // coalesced 256 B f1 row -> LDS fp32
      unsigned int u = ((const unsigned int*)(F1bf + (size_t)q * CCH))[t];
      sm.pn.f1s[2 * t]     = bflo(u);
      sm.pn.f1s[2 * t + 1] = bfhi(u);
    }
    int x2 = X2[q], y2 = Y2[q];            // L2-broadcast
    __syncthreads();

    if (t < 2 * (NPOS + NNEG)) {           // 218 threads: 2 per offset, 64 ch each
      int off = t >> 1, half = t & 1;
      int di = (off < NPOS) ? POS_I[off] : NEG_I[off - NPOS];
      int dj = (off < NPOS) ? POS_J[off] : NEG_J[off - NPOS];
      int xk = min(max(x2 + di, 0), WW - 1);
      int yk = min(max(y2 + dj, 0), HH - 1);
      const uint4* p4 = (const uint4*)(feat2T +
          ((size_t)((b * HH + yk) * WW) + xk) * CCH + half * 64);
      float acc = 0.f;
      #pragma unroll
      for (int i = 0; i < 8; ++i) {        // 8 x 16 B contiguous bf16
        uint4 v = p4[i];
        float4 fa = *(const float4*)&sm.pn.f1s[half * 64 + i * 8];
        float4 fb = *(const float4*)&sm.pn.f1s[half * 64 + i * 8 + 4];
        acc += fa.x * bflo(v.x) + fa.y * bfhi(v.x)
             + fa.z * bflo(v.y) + fa.w * bfhi(v.y)
             + fb.x * bflo(v.z) + fb.y * bfhi(v.z)
             + fb.z * bflo(v.w) + fb.w * bfhi(v.w);
      }
      acc += __shfl_xor(acc, 1);           // combine halves (adjacent lanes)
      if (half == 0) {
        if (off < NPOS) sm.pn.posv[off] = acc;
        else            sm.pn.negv[off - NPOS] = acc;
      }
    }
    if (t == 0)
      gt[(size_t)q * SCOLS] = 1.0f;        // rest of gt row is memset-zero
    __syncthreads();

    if (t == 0) {
      float best = sm.pn.posv[0]; int bi = 0;
      for (int k = 1; k < NPOS; ++k)
        if (sm.pn.posv[k] > best) { best = sm.pn.posv[k]; bi = k; }  // first occurrence
      sm.pn.bestv = best;
      int sx = min(max(x2 + POS_I[bi], 0), WW - 1);
      int sy = min(max(y2 + POS_J[bi], 0), HH - 1);
      float c1 = conf1[((size_t)b * HH + y) * WW + x];
      float c2 = conf2[((size_t)b * HH + sy) * WW + sx];
      qconf_out[q] = 0.5f * (c1 + c2);
    }
    __syncthreads();

    if (t < 1 + NNEG)                      // coalesced 324 B head write
      scores[(size_t)q * SCOLS + t] = (t == 0) ? sm.pn.bestv : sm.pn.negv[t - 1];

  } else {
    // ---------------- dscore branch (bf16 MFMA 64q x 64d) ----------------
    int bid = blockIdx.x - QTOT;
    int qb = (bid / DT64) * 64;
    int db = (bid % DT64) * 64;
    int w = threadIdx.x >> 6, lane = threadIdx.x & 63;
    int m  = lane & 15;
    int ko = (lane >> 4) * 8;

    if (threadIdx.x < 64) {
      sm.ds.sx2[threadIdx.x] = X2[qb + threadIdx.x];
      sm.ds.sy2[threadIdx.x] = Y2[qb + threadIdx.x];
    }

    f4v acc[4];
    #pragma unroll
    for (int dt = 0; dt < 4; ++dt) acc[dt] = (f4v){0.f, 0.f, 0.f, 0.f};

    #pragma unroll
    for (int kk = 0; kk < 4; ++kk) {
      s8v a = *(const s8v*)(F1bf + (size_t)(qb + w * 16 + m) * CCH + kk * 32 + ko);
      #pragma unroll
      for (int dt = 0; dt < 4; ++dt) {
        s8v bfr = *(const s8v*)(F2bf + (size_t)(db + dt * 16 + m) * CCH + kk * 32 + ko);
        acc[dt] = __builtin_amdgcn_mfma_f32_16x16x32_bf16(a, bfr, acc[dt], 0, 0, 0);
      }
    }

    // Stage to LDS (C/D layout: col = lane&15, row = (lane>>4)*4 + reg).
    int rbase = (lane >> 4) * 4, col = lane & 15;
    #pragma unroll
    for (int dt = 0; dt < 4; ++dt)
      #pragma unroll
      for (int r = 0; r < 4; ++r)
        sm.ds.tile[w * 16 + rbase + r][dt * 16 + col] = acc[dt][r];
    __syncthreads();

    // Vectorized epilogue: thread owns 4 cols x 4 row-passes -> dwordx4 stores.
    // scores only — gt distractor region is constant 0 and comes from memset.
    int col4  = (threadIdx.x & 15) * 4;
    int rslot = threadIdx.x >> 4;          // 0..15
    int dxs[4], dys[4], dbats[4];
    #pragma unroll
    for (int k = 0; k < 4; ++k) {
      int d = db + col4 + k;
      int dbat = d / (H1 * W1), dr = d % (H1 * W1);
      dys[k] = 16 + 8 * (dr / W1);
      dxs[k] = 16 + 8 * (dr % W1);
      dbats[k] = dbat;
    }
    #pragma unroll
    for (int p = 0; p < 4; ++p) {
      int row = p * 16 + rslot;
      int q = qb + row;
      int qbat = q / (H1 * W1);
      int sx = sm.ds.sx2[row], sy = sm.ds.sy2[row];
      f4raw vv = *(const f4raw*)&sm.ds.tile[row][col4];   // 16B-aligned b128
      #pragma unroll
      for (int k = 0; k < 4; ++k) {
        int ddx = dxs[k] - sx, ddy = dys[k] - sy;
        int dis2 = ddx * ddx + ddy * ddy + (dbats[k] != qbat ? 25 : 0);  // NEG_D^2
        if (dis2 < 25) vv[k] = 0.f;
      }
      size_t o = (size_t)q * SCOLS + 1 + NNEG + db + col4;  // 4B-aligned (SCOLS odd)
      __builtin_nontemporal_store(vv, (f4u*)&scores[o]);
    }
  }
}

extern "C" void kernel_launch(void* const* d_in, const int* in_sizes, int n_in,
                              void* d_out, int out_size, void* d_ws, size_t ws_size,
                              hipStream_t stream) {
  const float* feat1 = (const float*)d_in[0];
  const float* feat2 = (const float*)d_in[1];
  const float* conf1 = (const float*)d_in[2];
  const float* conf2 = (const float*)d_in[3];
  const float* aflow = (const float*)d_in[4];

  float* out       = (float*)d_out;
  float* scores    = out;
  float* gt        = out + (size_t)QTOT * SCOLS;
  float* mask_out  = out + 2 * (size_t)QTOT * SCOLS;
  float* qconf_out = mask_out + QTOT;

  unsigned short* feat2T = (unsigned short*)d_ws;                 // B*H*W*C bf16
  unsigned short* F1bf   = feat2T + (size_t)BB * HH * WW * CCH;
  unsigned short* F2bf   = F1bf + (size_t)QTOT * CCH;
  int* X2 = (int*)(F2bf + (size_t)QTOT * CCH);
  int* Y2 = X2 + QTOT;

  // gt body is constant zero: fill-engine memset (graph-capturable memset node)
  // replaces ~10M scalar stores in main_kernel. Kernels then write only gt[q][0].
  hipMemsetAsync(gt, 0, (size_t)QTOT * SCOLS * sizeof(float), stream);

  dim3 gT(WW / 32, HH / 2, BB);
  transpose_kernel<<<gT, 256, 0, stream>>>(feat2, feat1, aflow, feat2T,
                                           F1bf, F2bf, X2, Y2, mask_out);
  main_kernel<<<QTOT + DT64 * QT64, 256, 0, stream>>>(feat2T, conf1, conf2,
                                                      F1bf, F2bf, X2, Y2,
                                                      scores, gt, qconf_out);
}

// Round 7
// 332.189 us; speedup vs baseline: 1.0981x; 1.0035x over previous
//
#include <hip/hip_runtime.h>

// NGH=7, SUBQ=8, SUBD=1, POS_D=3, NEG_D=5, BORDER=16, SUBD_NEG=8. B=4,C=128,H=W=256.
#define CCH   128
#define HH    256
#define WW    256
#define BB    4
#define H1    28
#define W1    28
#define QTOT  3136
#define NPOS  29
#define NNEG  80
#define NDIS  3136
#define DT64  (NDIS / 64)   // 49 distractor tiles
#define QT64  (QTOT / 64)   // 49 query tiles
#define SCOLS 3217          // 1 + NNEG + NDIS

typedef short s8v __attribute__((ext_vector_type(8)));   // 8 bf16 (4 VGPRs)
typedef float f4v __attribute__((ext_vector_type(4)));   // MFMA accumulator
typedef float f4raw __attribute__((ext_vector_type(4))); // nontemporal-load-safe f32x4
typedef float f4u __attribute__((ext_vector_type(4), aligned(4)));  // 4B-aligned f32x4
typedef unsigned int u2v __attribute__((ext_vector_type(2)));

__device__ __forceinline__ unsigned short f2bf(float f) {  // RNE fp32->bf16
  unsigned int u = __float_as_uint(f);
  u += 0x7fffu + ((u >> 16) & 1u);
  return (unsigned short)(u >> 16);
}
__device__ __forceinline__ float bflo(unsigned int v) { return __uint_as_float(v << 16); }
__device__ __forceinline__ float bfhi(unsigned int v) { return __uint_as_float(v & 0xffff0000u); }

// Offsets in exact reference enumeration order (j outer asc, i inner asc).
__constant__ int POS_I[NPOS] = {
  0, -2,-1,0,1,2, -2,-1,0,1,2, -3,-2,-1,0,1,2,3, -2,-1,0,1,2, -2,-1,0,1,2, 0};
__constant__ int POS_J[NPOS] = {
  -3, -2,-2,-2,-2,-2, -1,-1,-1,-1,-1, 0,0,0,0,0,0,0, 1,1,1,1,1, 2,2,2,2,2, 3};
__constant__ int NEG_I[NNEG] = {
  0, -3,-2,-1,0,1,2,3, -4,-3,-2,-1,0,1,2,3,4, -5,-4,-3,3,4,5, -6,-5,-4,4,5,6,
  -6,-5,5,6, -6,-5,5,6, -7,-6,-5,5,6,7, -6,-5,5,6, -6,-5,5,6, -6,-5,-4,4,5,6,
  -5,-4,-3,3,4,5, -4,-3,-2,-1,0,1,2,3,4, -3,-2,-1,0,1,2,3, 0};
__constant__ int NEG_J[NNEG] = {
  -7, -6,-6,-6,-6,-6,-6,-6, -5,-5,-5,-5,-5,-5,-5,-5,-5, -4,-4,-4,-4,-4,-4,
  -3,-3,-3,-3,-3,-3, -2,-2,-2,-2, -1,-1,-1,-1, 0,0,0,0,0,0, 1,1,1,1, 2,2,2,2,
  3,3,3,3,3,3, 4,4,4,4,4,4, 5,5,5,5,5,5,5,5,5, 6,6,6,6,6,6,6, 7};

// ---- Kernel T: feat2 NCHW fp32 -> NHWC bf16, fused F1bf/F2bf/xy2/mask staging ----
// v2.1: launch_bounds(256) only — the previous (256,6) forced VGPR<=~84 while the
// 8 buffered float4 loads need 32 VGPRs + temps, likely spilling to scratch
// (~128B/thread = ~128MB extra HBM) and cancelling the latency-hiding win.
__global__ __launch_bounds__(256)
void transpose_kernel(const float* __restrict__ feat2,
                      const float* __restrict__ feat1,
                      const float* __restrict__ aflow,
                      unsigned short* __restrict__ feat2T,
                      unsigned short* __restrict__ F1bf,
                      unsigned short* __restrict__ F2bf,
                      int* __restrict__ X2, int* __restrict__ Y2,
                      float* __restrict__ mask_out) {
  // stride 66 dwords: store banks = (8*xq + cp) % 32 -> 2 lanes/bank (free);
  // read b64 banks: exactly 4 dwords/bank/instr = LDS throughput minimum.
  __shared__ __align__(16) unsigned int tile[2][32][66];

  int x0 = blockIdx.x * 32;
  int y0 = blockIdx.y * 2;
  int b  = blockIdx.z;
  int tid = threadIdx.x;
  int cp = tid >> 3;        // channel-pair index within half (0..31)
  int xq = tid & 7;         // float4 quad within 32-wide x tile

  // Phase 1: issue all 8 float4 loads before any use (8 VMEM in flight/thread).
  const float* fbase = feat2 + (size_t)b * CCH * HH * WW;
  f4raw v[2][2][2];         // [row][half][c parity]
  #pragma unroll
  for (int r = 0; r < 2; ++r)
    #pragma unroll
    for (int h = 0; h < 2; ++h) {
      int c0 = 2 * (h * 32 + cp);
      const float* p = fbase + ((size_t)c0 * HH + (y0 + r)) * WW + x0 + 4 * xq;
      v[r][h][0] = __builtin_nontemporal_load((const f4raw*)p);
      v[r][h][1] = __builtin_nontemporal_load((const f4raw*)(p + (size_t)HH * WW));
    }

  // Convert + packed dword stores (channel pair -> one LDS dword).
  #pragma unroll
  for (int r = 0; r < 2; ++r)
    #pragma unroll
    for (int h = 0; h < 2; ++h) {
      int cpf = h * 32 + cp;
      f4raw a = v[r][h][0], c = v[r][h][1];
      tile[r][4 * xq + 0][cpf] = (unsigned)f2bf(a.x) | ((unsigned)f2bf(c.x) << 16);
      tile[r][4 * xq + 1][cpf] = (unsigned)f2bf(a.y) | ((unsigned)f2bf(c.y) << 16);
      tile[r][4 * xq + 2][cpf] = (unsigned)f2bf(a.z) | ((unsigned)f2bf(c.z) << 16);
      tile[r][4 * xq + 3][cpf] = (unsigned)f2bf(a.w) | ((unsigned)f2bf(c.w) << 16);
    }
  __syncthreads();

  // Phase 2: each thread emits 32 B (16 channels) of one pixel, b64 LDS reads.
  int xi = tid >> 3;        // 0..31
  int cg = (tid & 7) * 8;   // dword index within the 64-dword channel row
  #pragma unroll
  for (int r = 0; r < 2; ++r) {
    u2v t0 = *(const u2v*)&tile[r][xi][cg + 0];
    u2v t1 = *(const u2v*)&tile[r][xi][cg + 2];
    u2v t2 = *(const u2v*)&tile[r][xi][cg + 4];
    u2v t3 = *(const u2v*)&tile[r][xi][cg + 6];
    unsigned int* dst = (unsigned int*)(feat2T +
        ((size_t)((b * HH + y0 + r) * WW) + x0 + xi) * CCH) + cg;
    ((uint4*)dst)[0] = make_uint4(t0.x, t0.y, t1.x, t1.y);
    ((uint4*)dst)[1] = make_uint4(t2.x, t2.y, t3.x, t3.y);
  }

  // Grid-point staging: F2bf straight from packed tile, F1bf from feat1,
  // xy2/mask from aflow. At most one qualifying row per block.
  #pragma unroll
  for (int r = 0; r < 2; ++r) {
    int y = y0 + r;
    if ((y & 7) == 0 && y >= 16 && y <= 232) {
      int xs = x0 + (tid >> 6) * 8;         // 4 grid-x candidates per block
      if (xs >= 16 && xs <= 232) {
        int cpq = tid & 63;                 // channel pair 0..63
        int q = b * H1 * W1 + ((y - 16) >> 3) * W1 + ((xs - 16) >> 3);
        ((unsigned int*)(F2bf + (size_t)q * CCH))[cpq] = tile[r][xs - x0][cpq];
        const float* f1p = feat1 + ((size_t)(b * CCH + 2 * cpq) * HH + y) * WW + xs;
        unsigned int l1 = f2bf(f1p[0]);
        unsigned int h1 = f2bf(f1p[(size_t)HH * WW]);
        ((unsigned int*)(F1bf + (size_t)q * CCH))[cpq] = l1 | (h1 << 16);
        if (cpq == 0) {
          float ax = aflow[((size_t)(b * 2 + 0) * HH + y) * WW + xs];
          float ay = aflow[((size_t)(b * 2 + 1) * HH + y) * WW + xs];
          int px = (int)(ax + 0.5f);
          int py = (int)(ay + 0.5f);
          X2[q] = px; Y2[q] = py;
          mask_out[q] = (px >= 0 && py >= 0 && px < WW && py < HH) ? 1.0f : 0.0f;
        }
      }
    }
  }
}

// ---- Kernel M: fused posneg (blocks 0..QTOT-1) + dscore (blocks QTOT..) ----
// gt is zeroed by hipMemsetAsync in kernel_launch; kernels write only gt[q][0]=1.
__global__ void main_kernel(const unsigned short* __restrict__ feat2T,
                            const float* __restrict__ conf1,
                            const float* __restrict__ conf2,
                            const unsigned short* __restrict__ F1bf,
                            const unsigned short* __restrict__ F2bf,
                            const int* __restrict__ X2, const int* __restrict__ Y2,
                            float* __restrict__ scores, float* __restrict__ gt,
                            float* __restrict__ qconf_out) {
  __shared__ union {
    // tile stride 68: rows 16B-aligned for b128 readout;
    // MFMA-stage banks: 68*4 dw = 272 ≡ 16 mod 32 -> 2 lanes/bank (free).
    struct { __align__(16) float tile[64][68]; int sx2[64]; int sy2[64]; } ds;
    struct { __align__(16) float f1s[CCH]; float posv[NPOS]; float negv[NNEG];
             float bestv; } pn;
  } sm;

  if (blockIdx.x < QTOT) {
    // ---------------- posneg branch ----------------
    int q = blockIdx.x, t = threadIdx.x;
    int b = q / (H1 * W1), r = q % (H1 * W1);
    int y = 16 + 8 * (r / W1);
    int x = 16 + 8 * (r % W1);

    if (t < 64) {                          // coalesced 256 B f1 row -> LDS fp32
      unsigned int u = ((const unsigned int*)(F1bf + (size_t)q * CCH))[t];
      sm.pn.f1s[2 * t]     = bflo(u);
      sm.pn.f1s[2 * t + 1] = bfhi(u);
    }
    int x2 = X2[q], y2 = Y2[q];            // L2-broadcast
    __syncthreads();

    if (t < 2 * (NPOS + NNEG)) {           // 218 threads: 2 per offset, 64 ch each
      int off = t >> 1, half = t & 1;
      int di = (off < NPOS) ? POS_I[off] : NEG_I[off - NPOS];
      int dj = (off < NPOS) ? POS_J[off] : NEG_J[off - NPOS];
      int xk = min(max(x2 + di, 0), WW - 1);
      int yk = min(max(y2 + dj, 0), HH - 1);
      const uint4* p4 = (const uint4*)(feat2T +
          ((size_t)((b * HH + yk) * WW) + xk) * CCH + half * 64);
      float acc = 0.f;
      #pragma unroll
      for (int i = 0; i < 8; ++i) {        // 8 x 16 B contiguous bf16
        uint4 v = p4[i];
        float4 fa = *(const float4*)&sm.pn.f1s[half * 64 + i * 8];
        float4 fb = *(const float4*)&sm.pn.f1s[half * 64 + i * 8 + 4];
        acc += fa.x * bflo(v.x) + fa.y * bfhi(v.x)
             + fa.z * bflo(v.y) + fa.w * bfhi(v.y)
             + fb.x * bflo(v.z) + fb.y * bfhi(v.z)
             + fb.z * bflo(v.w) + fb.w * bfhi(v.w);
      }
      acc += __shfl_xor(acc, 1);           // combine halves (adjacent lanes)
      if (half == 0) {
        if (off < NPOS) sm.pn.posv[off] = acc;
        else            sm.pn.negv[off - NPOS] = acc;
      }
    }
    if (t == 0)
      gt[(size_t)q * SCOLS] = 1.0f;        // rest of gt row is memset-zero
    __syncthreads();

    if (t == 0) {
      float best = sm.pn.posv[0]; int bi = 0;
      for (int k = 1; k < NPOS; ++k)
        if (sm.pn.posv[k] > best) { best = sm.pn.posv[k]; bi = k; }  // first occurrence
      sm.pn.bestv = best;
      int sx = min(max(x2 + POS_I[bi], 0), WW - 1);
      int sy = min(max(y2 + POS_J[bi], 0), HH - 1);
      float c1 = conf1[((size_t)b * HH + y) * WW + x];
      float c2 = conf2[((size_t)b * HH + sy) * WW + sx];
      qconf_out[q] = 0.5f * (c1 + c2);
    }
    __syncthreads();

    if (t < 1 + NNEG)                      // coalesced 324 B head write
      scores[(size_t)q * SCOLS + t] = (t == 0) ? sm.pn.bestv : sm.pn.negv[t - 1];

  } else {
    // ---------------- dscore branch (bf16 MFMA 64q x 64d) ----------------
    int bid = blockIdx.x - QTOT;
    int qb = (bid / DT64) * 64;
    int db = (bid % DT64) * 64;
    int w = threadIdx.x >> 6, lane = threadIdx.x & 63;
    int m  = lane & 15;
    int ko = (lane >> 4) * 8;

    if (threadIdx.x < 64) {
      sm.ds.sx2[threadIdx.x] = X2[qb + threadIdx.x];
      sm.ds.sy2[threadIdx.x] = Y2[qb + threadIdx.x];
    }

    f4v acc[4];
    #pragma unroll
    for (int dt = 0; dt < 4; ++dt) acc[dt] = (f4v){0.f, 0.f, 0.f, 0.f};

    #pragma unroll
    for (int kk = 0; kk < 4; ++kk) {
      s8v a = *(const s8v*)(F1bf + (size_t)(qb + w * 16 + m) * CCH + kk * 32 + ko);
      #pragma unroll
      for (int dt = 0; dt < 4; ++dt) {
        s8v bfr = *(const s8v*)(F2bf + (size_t)(db + dt * 16 + m) * CCH + kk * 32 + ko);
        acc[dt] = __builtin_amdgcn_mfma_f32_16x16x32_bf16(a, bfr, acc[dt], 0, 0, 0);
      }
    }

    // Stage to LDS (C/D layout: col = lane&15, row = (lane>>4)*4 + reg).
    int rbase = (lane >> 4) * 4, col = lane & 15;
    #pragma unroll
    for (int dt = 0; dt < 4; ++dt)
      #pragma unroll
      for (int r = 0; r < 4; ++r)
        sm.ds.tile[w * 16 + rbase + r][dt * 16 + col] = acc[dt][r];
    __syncthreads();

    // Vectorized epilogue: thread owns 4 cols x 4 row-passes -> dwordx4 stores.
    // scores only — gt distractor region is constant 0 and comes from memset.
    int col4  = (threadIdx.x & 15) * 4;
    int rslot = threadIdx.x >> 4;          // 0..15
    int dxs[4], dys[4], dbats[4];
    #pragma unroll
    for (int k = 0; k < 4; ++k) {
      int d = db + col4 + k;
      int dbat = d / (H1 * W1), dr = d % (H1 * W1);
      dys[k] = 16 + 8 * (dr / W1);
      dxs[k] = 16 + 8 * (dr % W1);
      dbats[k] = dbat;
    }
    #pragma unroll
    for (int p = 0; p < 4; ++p) {
      int row = p * 16 + rslot;
      int q = qb + row;
      int qbat = q / (H1 * W1);
      int sx = sm.ds.sx2[row], sy = sm.ds.sy2[row];
      f4raw vv = *(const f4raw*)&sm.ds.tile[row][col4];   // 16B-aligned b128
      #pragma unroll
      for (int k = 0; k < 4; ++k) {
        int ddx = dxs[k] - sx, ddy = dys[k] - sy;
        int dis2 = ddx * ddx + ddy * ddy + (dbats[k] != qbat ? 25 : 0);  // NEG_D^2
        if (dis2 < 25) vv[k] = 0.f;
      }
      size_t o = (size_t)q * SCOLS + 1 + NNEG + db + col4;  // 4B-aligned (SCOLS odd)
      __builtin_nontemporal_store(vv, (f4u*)&scores[o]);
    }
  }
}

extern "C" void kernel_launch(void* const* d_in, const int* in_sizes, int n_in,
                              void* d_out, int out_size, void* d_ws, size_t ws_size,
                              hipStream_t stream) {
  const float* feat1 = (const float*)d_in[0];
  const float* feat2 = (const float*)d_in[1];
  const float* conf1 = (const float*)d_in[2];
  const float* conf2 = (const float*)d_in[3];
  const float* aflow = (const float*)d_in[4];

  float* out       = (float*)d_out;
  float* scores    = out;
  float* gt        = out + (size_t)QTOT * SCOLS;
  float* mask_out  = out + 2 * (size_t)QTOT * SCOLS;
  float* qconf_out = mask_out + QTOT;

  unsigned short* feat2T = (unsigned short*)d_ws;                 // B*H*W*C bf16
  unsigned short* F1bf   = feat2T + (size_t)BB * HH * WW * CCH;
  unsigned short* F2bf   = F1bf + (size_t)QTOT * CCH;
  int* X2 = (int*)(F2bf + (size_t)QTOT * CCH);
  int* Y2 = X2 + QTOT;

  // gt body is constant zero: fill-engine memset (graph-capturable memset node)
  // replaces ~10M scalar stores in main_kernel. Kernels then write only gt[q][0].
  hipMemsetAsync(gt, 0, (size_t)QTOT * SCOLS * sizeof(float), stream);

  dim3 gT(WW / 32, HH / 2, BB);
  transpose_kernel<<<gT, 256, 0, stream>>>(feat2, feat1, aflow, feat2T,
                                           F1bf, F2bf, X2, Y2, mask_out);
  main_kernel<<<QTOT + DT64 * QT64, 256, 0, stream>>>(feat2T, conf1, conf2,
                                                      F1bf, F2bf, X2, Y2,
                                                      scores, gt, qconf_out);
}